// Round 4
// baseline (77.658 us; speedup 1.0000x reference)
//
#include <hip/hip_runtime.h>
#include <math.h>

#define HH 480
#define WW 640
#define WP (WW + 8)           /* padded LDS row stride; data at +4, halos at 3 and 4+WW */
#define NL 100
#define NREF 20
#define RPB 2                 /* rows per block */
#define NB (HH / RPB)         /* 240 blocks */

// ws layout: PART only. partial[col][block], col = t*4+q (80 cols),
// col stride NB floats (960 B, 16B-aligned). ~76.8 KB. No zeroing needed:
// every entry is plain-stored by its owning block. NO atomics, NO fences —
// the kernel boundary (stream order) provides cross-XCD coherence for free.
// R7: explicit __threadfence costs ~50 µs (L2 writeback storms).
// R9: single-dispatch fusion (sc1 stores + ticket election) REGRESSED
// 78.2→81.2 — elected block's uncached agent-scope re-read tail outweighs
// the ~3 µs dispatch+drain saving. Two dispatches is the right structure.
// R10: valid de-staged; R11: valid preloaded to regs (ride barrier wait): 75.5.
// R12 (this round), value-preserving scheduling only (accumulation order,
// pixel->lane map, shfl tree all pinned for bitwise-identical output):
//  (a) rank computed from UNIFORM global score reads (s_load path) between
//      staging-issue and barrier 1 -> serial rank segment hides under depth
//      latency; prologue drops from 3 barriers to 2; s_sc removed.
//  (b) zero-padded LDS halo columns -> per-pixel edge masking (6 muls,
//      clamps, cmps) deleted; rm[0]*0.f == halo +0.0 bitwise through all
//      downstream sub/add/fma. 8 ds_reads/pixel share one vaddr + imm offs.
// RPB=2 beats RPB=1 (R6 79.1 vs R8 82.2).

__global__ __launch_bounds__(256) void plane_main_kernel(
    const float* __restrict__ depth, const int* __restrict__ valid,
    const float* __restrict__ line_pred, const float* __restrict__ line_score,
    float* __restrict__ w) {
    __shared__ float ds[(RPB + 2) * WP];   // rows base-1 .. base+RPB, halo-padded
    __shared__ float s_vert[NREF][6];      // vx,vy x 3 per rank
    __shared__ float s_ae[RPB][NREF * 3];  // per-row edge constant
    __shared__ float s_ey[NREF * 3];

    const int tid = threadIdx.x;
    const int base = blockIdx.x * RPB;
    const int wid = tid >> 6, lane = tid & 63;

    // preload valid into registers FIRST: latency overlaps the depth staging
    // wait at the first barrier instead of stalling the compute loop.
    int vreg[RPB][10];
    {
        const int* vb = valid + base * WW + lane;
        #pragma unroll
        for (int rr = 0; rr < RPB; rr++)
            #pragma unroll
            for (int j = 0; j < 10; j++)
                vreg[rr][j] = vb[rr * WW + j * 64];
    }

    // stage depth: (RPB+2) rows x 160 float4 into padded rows (data at +4,
    // 16B-aligned since WP*4 = 2592 is a multiple of 16)
    for (int idx = tid; idx < (RPB + 2) * (WW / 4); idx += 256) {
        const int lr = idx / (WW / 4);
        const int c4 = idx - lr * (WW / 4);
        const int g = base - 1 + lr;
        float4 v = make_float4(0.f, 0.f, 0.f, 0.f);
        if ((unsigned)g < (unsigned)HH) v = ((const float4*)depth)[g * (WW / 4) + c4];
        ((float4*)ds)[lr * (WP / 4) + 1 + c4] = v;
    }
    // zero the two halo columns of each staged row (read as x=-1 / x=WW)
    if (tid < (RPB + 2) * 2) {
        const int row = tid >> 1;
        ds[row * WP + ((tid & 1) ? (4 + WW) : 3)] = 0.f;
    }

    // rank + vertex setup BEFORE the barrier: score reads are wave-uniform ->
    // scalar loads; the ~100-compare loop hides under depth staging latency.
    // Stable rank == jax.lax.top_k order (desc, ties -> lower idx).
    if (tid < NL) {
        const float s0 = line_score[2 * tid];
        int rank = 0;
        #pragma unroll 4
        for (int j = 0; j < NL; j++) {
            const float sj = line_score[2 * j];   // uniform -> s_load
            rank += ((sj > s0) || (sj == s0 && j < tid)) ? 1 : 0;
        }
        if (rank < NREF) {
            const float2 c01 = ((const float2*)line_pred)[3 * tid];
            const float2 c23 = ((const float2*)line_pred)[3 * tid + 1];
            const float2 c45 = ((const float2*)line_pred)[3 * tid + 2];
            // round half-even == jnp.round; clip to image
            s_vert[rank][0] = fminf(fmaxf(rintf(c01.x * (float)WW), 0.f), (float)(WW - 1));
            s_vert[rank][1] = fminf(fmaxf(rintf(c01.y * (float)HH), 0.f), (float)(HH - 1));
            s_vert[rank][2] = fminf(fmaxf(rintf(c23.x * (float)WW), 0.f), (float)(WW - 1));
            s_vert[rank][3] = fminf(fmaxf(rintf(c23.y * (float)HH), 0.f), (float)(HH - 1));
            s_vert[rank][4] = fminf(fmaxf(rintf(c45.x * (float)WW), 0.f), (float)(WW - 1));
            s_vert[rank][5] = fminf(fmaxf(rintf(c45.y * (float)HH), 0.f), (float)(HH - 1));
        }
    }
    __syncthreads();   // covers depth LDS writes + halo zeros + s_vert

    // per-row edge constants: d_e(px) = ae_e - ey_e*px (exact: integer fp32
    // operands, |terms| < 2^22 -> sign test bitwise-identical to reference)
    if (tid < NREF * 3) {
        const int t = tid / 3, e = tid - 3 * t, n = (e + 1) % 3;
        const float vx = s_vert[t][2 * e], vy = s_vert[t][2 * e + 1];
        const float ex = s_vert[t][2 * n] - vx, eyv = s_vert[t][2 * n + 1] - vy;
        s_ey[tid] = eyv;
        #pragma unroll
        for (int rr = 0; rr < RPB; rr++)
            s_ae[rr][tid] = fmaf(ex, (float)(base + rr) - vy, eyv * vx);
    }
    __syncthreads();

    float eyr[5][3];
    #pragma unroll
    for (int i = 0; i < 5; i++)
        #pragma unroll
        for (int e = 0; e < 3; e++)
            eyr[i][e] = s_ey[(wid * 5 + i) * 3 + e];

    float acc[5][4];
    #pragma unroll
    for (int i = 0; i < 5; i++)
        #pragma unroll
        for (int q = 0; q < 4; q++) acc[i][q] = 0.f;

    #pragma unroll
    for (int rr = 0; rr < RPB; rr++) {
        float ae[5][3];
        #pragma unroll
        for (int i = 0; i < 5; i++)
            #pragma unroll
            for (int e = 0; e < 3; e++)
                ae[i][e] = s_ae[rr][(wid * 5 + i) * 3 + e];
        // rm[x] = col x-1 of sobel-top row, rm[x+1] = col x, rm[x+2] = col x+1
        const float* rm = ds + rr * WP + 3;
        const float* rc = rm + WP;
        const float* rp = rc + WP;
        #pragma unroll
        for (int j = 0; j < 10; j++) {
            const int x = j * 64 + lane;
            const float px = (float)x;
            const float a00 = rm[x], a01 = rm[x + 1], a02 = rm[x + 2];
            const float a10 = rc[x],                   a12 = rc[x + 2];
            const float a20 = rp[x], a21 = rp[x + 1], a22 = rp[x + 2];
            // XLA conv = cross-correlation, zero pad (halo columns hold +0.0)
            const float gx = (a00 - a02) + 2.f * (a10 - a12) + (a20 - a22);
            const float gy = (a00 + 2.f * a01 + a02) - (a20 + 2.f * a21 + a22);
            const float nx = -gx, ny = -gy;
            const float s2 = nx * nx + ny * ny;
            const bool vm = (vreg[rr][j] != 0);
            #pragma unroll
            for (int i = 0; i < 5; i++) {
                const float d0 = fmaf(-eyr[i][0], px, ae[i][0]);
                const float d1 = fmaf(-eyr[i][1], px, ae[i][1]);
                const float d2 = fmaf(-eyr[i][2], px, ae[i][2]);
                const float dmin = fminf(fminf(d0, d1), d2);
                const float dmax = fmaxf(fmaxf(d0, d1), d2);
                const bool m = ((dmin >= 0.f) | (dmax <= 0.f)) & vm;
                const float mf = m ? 1.f : 0.f;
                acc[i][0] += mf;
                acc[i][1] = fmaf(mf, nx, acc[i][1]);
                acc[i][2] = fmaf(mf, ny, acc[i][2]);
                acc[i][3] = fmaf(mf, s2, acc[i][3]);
            }
        }
    }

    // wave-level reduction; waves own disjoint triangles -> no cross-wave step
    #pragma unroll
    for (int off = 32; off > 0; off >>= 1)
        #pragma unroll
        for (int i = 0; i < 5; i++)
            #pragma unroll
            for (int q = 0; q < 4; q++)
                acc[i][q] += __shfl_down(acc[i][q], off);
    if (lane == 0) {
        // plain stores, zero contention: col = (wid*5+i)*4+q, row = blockIdx.x
        #pragma unroll
        for (int i = 0; i < 5; i++)
            #pragma unroll
            for (int q = 0; q < 4; q++)
                w[((wid * 5 + i) * 4 + q) * NB + blockIdx.x] = acc[i][q];
    }
}

__global__ __launch_bounds__(128) void plane_finalize_kernel(
    const float* __restrict__ line_score, const float* __restrict__ w,
    float* __restrict__ out) {
    __shared__ float s_col[NREF * 4];
    __shared__ int s_cnt[2];
    const int tid = threadIdx.x; // 0..127
    const int lane = tid & 63, wid = tid >> 6;

    // sum partial columns FIRST so the loads issue before the ballot work.
    // (NB contiguous floats each, float4). unroll 15: 15 independent float4
    // loads in flight -> 4 latency round trips. Accumulation order is the
    // same strictly-sequential per-lane order -> bitwise-identical result.
    if (tid < NREF * 4) {
        const float4* col = (const float4*)(w + tid * NB);
        float4 s4 = make_float4(0.f, 0.f, 0.f, 0.f);
        #pragma unroll 15
        for (int p = 0; p < NB / 4; p++) {
            const float4 v = col[p];
            s4.x += v.x; s4.y += v.y; s4.z += v.z; s4.w += v.w;
        }
        s_col[tid] = (s4.x + s4.y) + (s4.z + s4.w);
    }

    // top_num = min(#(softmax prob0 > 0.6), 20); include-flag = (rank < top_num)
    int flag = 0;
    if (tid < NL) {
        const float2 sc = ((const float2*)line_score)[tid];
        const float p0 = 1.0f / (1.0f + expf(sc.y - sc.x));
        flag = (p0 > 0.6f) ? 1 : 0;
    }
    const unsigned long long b = __ballot(flag);
    if (lane == 0) s_cnt[wid] = __popcll(b);
    __syncthreads();

    const int topnum = min(s_cnt[0] + s_cnt[1], NREF);
    float val = 0.f, inc = 0.f;
    if (tid < NREF) {
        const float c  = s_col[tid * 4 + 0];
        const float sx = s_col[tid * 4 + 1];
        const float sy = s_col[tid * 4 + 2];
        const float sq = s_col[tid * 4 + 3];
        const float safe = fmaxf(c, 1.f);
        const float mx = sx / safe, my = sy / safe;
        // (var_x+var_y) expanded; exact 0 when c==0
        const float var = (sq - 2.f * mx * sx - 2.f * my * sy
                           + c * (mx * mx + my * my)) / safe;
        inc = ((c >= 100.f) && (tid < topnum)) ? 1.f : 0.f;
        val = inc * var;
    }
    if (tid < 64) { // lanes 20..63 carry zeros
        #pragma unroll
        for (int off = 32; off > 0; off >>= 1) {
            val += __shfl_down(val, off);
            inc += __shfl_down(inc, off);
        }
        if (tid == 0) out[0] = val / fmaxf(inc, 1.f);
    }
}

extern "C" void kernel_launch(void* const* d_in, const int* in_sizes, int n_in,
                              void* d_out, int out_size, void* d_ws, size_t ws_size,
                              hipStream_t stream) {
    const float* depth_pred = (const float*)d_in[0];
    // d_in[1] = depth_gt (unused by reference)
    const float* line_pred  = (const float*)d_in[2];
    const float* line_score = (const float*)d_in[3];
    const int*   valid_mask = (const int*)d_in[4];
    float* out = (float*)d_out;
    float* w = (float*)d_ws;

    plane_main_kernel<<<NB, 256, 0, stream>>>(depth_pred, valid_mask,
                                              line_pred, line_score, w);
    plane_finalize_kernel<<<1, 128, 0, stream>>>(line_score, w, out);
}

// Round 5
// 76.497 us; speedup vs baseline: 1.0152x; 1.0152x over previous
//
#include <hip/hip_runtime.h>
#include <math.h>

#define HH 480
#define WW 640
#define NL 100
#define NREF 20
#define RPB 2                 /* rows per block */
#define NB (HH / RPB)         /* 240 blocks */

// ws layout: PART only. partial[col][block], col = t*4+q (80 cols),
// col stride NB floats (960 B, 16B-aligned). ~76.8 KB. No zeroing needed:
// every entry is plain-stored by its owning block. NO atomics, NO fences —
// the kernel boundary (stream order) provides cross-XCD coherence for free.
// R7: explicit __threadfence costs ~50 µs (L2 writeback storms).
// R9: single-dispatch fusion (sc1 stores + ticket election) REGRESSED
// 78.2→81.2 — elected block's uncached agent-scope re-read tail outweighs
// the ~3 µs dispatch+drain saving. Two dispatches is the right structure.
// R10: valid de-staged; R11: valid preloaded to regs (ride barrier wait): 75.5.
// R12: rank-before-barrier + halo-padded LDS REGRESSED 75.5→77.7 — the
// 100-iter rank loop on the scalar-cache path (first-touch miss + dependent
// s_load chain) became the exposed prologue critical path, replacing the
// hidden 0.3 µs LDS-fed segment; halo pad attacked VALU that was already
// latency-hidden. REVERTED to the R11 structure (this file == R11, best
// verified 75.46 µs).
// RPB=2 beats RPB=1 (R6 79.1 vs R8 82.2): half the halo staging, half the
// rank-loop instances, half the partial matrix.

__global__ __launch_bounds__(256) void plane_main_kernel(
    const float* __restrict__ depth, const int* __restrict__ valid,
    const float* __restrict__ line_pred, const float* __restrict__ line_score,
    float* __restrict__ w) {
    __shared__ float ds[(RPB + 2) * WW];   // rows base-1 .. base+RPB (zero-filled OOB)
    __shared__ float s_sc[NL];
    __shared__ float s_vert[NREF][6];      // vx,vy x 3 per rank
    __shared__ float s_ae[RPB][NREF * 3];  // per-row edge constant
    __shared__ float s_ey[NREF * 3];

    const int tid = threadIdx.x;
    const int base = blockIdx.x * RPB;
    const int wid = tid >> 6, lane = tid & 63;

    // preload valid into registers FIRST: latency overlaps the depth staging
    // wait at the first barrier instead of stalling the compute loop.
    int vreg[RPB][10];
    {
        const int* vb = valid + base * WW + lane;
        #pragma unroll
        for (int rr = 0; rr < RPB; rr++)
            #pragma unroll
            for (int j = 0; j < 10; j++)
                vreg[rr][j] = vb[rr * WW + j * 64];
    }

    if (tid < NL) s_sc[tid] = ((const float2*)line_score)[tid].x;

    // stage depth: (RPB+2) rows x 160 float4
    for (int idx = tid; idx < (RPB + 2) * (WW / 4); idx += 256) {
        const int lr = idx / (WW / 4);
        const int c4 = idx - lr * (WW / 4);
        const int g = base - 1 + lr;
        float4 v = make_float4(0.f, 0.f, 0.f, 0.f);
        if ((unsigned)g < (unsigned)HH) v = ((const float4*)depth)[g * (WW / 4) + c4];
        ((float4*)ds)[idx] = v;
    }
    __syncthreads();

    // stable rank == jax.lax.top_k order (desc, ties -> lower idx); permutation
    if (tid < NL) {
        const float s0 = s_sc[tid];
        int rank = 0;
        for (int j = 0; j < NL; j++) {
            const float sj = s_sc[j];
            rank += ((sj > s0) || (sj == s0 && j < tid)) ? 1 : 0;
        }
        if (rank < NREF) {
            const float2 c01 = ((const float2*)line_pred)[3 * tid];
            const float2 c23 = ((const float2*)line_pred)[3 * tid + 1];
            const float2 c45 = ((const float2*)line_pred)[3 * tid + 2];
            // round half-even == jnp.round; clip to image
            s_vert[rank][0] = fminf(fmaxf(rintf(c01.x * (float)WW), 0.f), (float)(WW - 1));
            s_vert[rank][1] = fminf(fmaxf(rintf(c01.y * (float)HH), 0.f), (float)(HH - 1));
            s_vert[rank][2] = fminf(fmaxf(rintf(c23.x * (float)WW), 0.f), (float)(WW - 1));
            s_vert[rank][3] = fminf(fmaxf(rintf(c23.y * (float)HH), 0.f), (float)(HH - 1));
            s_vert[rank][4] = fminf(fmaxf(rintf(c45.x * (float)WW), 0.f), (float)(WW - 1));
            s_vert[rank][5] = fminf(fmaxf(rintf(c45.y * (float)HH), 0.f), (float)(HH - 1));
        }
    }
    __syncthreads();

    // per-row edge constants: d_e(px) = ae_e - ey_e*px (exact: integer fp32
    // operands, |terms| < 2^22 -> sign test bitwise-identical to reference)
    if (tid < NREF * 3) {
        const int t = tid / 3, e = tid - 3 * t, n = (e + 1) % 3;
        const float vx = s_vert[t][2 * e], vy = s_vert[t][2 * e + 1];
        const float ex = s_vert[t][2 * n] - vx, eyv = s_vert[t][2 * n + 1] - vy;
        s_ey[tid] = eyv;
        #pragma unroll
        for (int rr = 0; rr < RPB; rr++)
            s_ae[rr][tid] = fmaf(ex, (float)(base + rr) - vy, eyv * vx);
    }
    __syncthreads();

    float eyr[5][3];
    #pragma unroll
    for (int i = 0; i < 5; i++)
        #pragma unroll
        for (int e = 0; e < 3; e++)
            eyr[i][e] = s_ey[(wid * 5 + i) * 3 + e];

    float acc[5][4];
    #pragma unroll
    for (int i = 0; i < 5; i++)
        #pragma unroll
        for (int q = 0; q < 4; q++) acc[i][q] = 0.f;

    #pragma unroll
    for (int rr = 0; rr < RPB; rr++) {
        float ae[5][3];
        #pragma unroll
        for (int i = 0; i < 5; i++)
            #pragma unroll
            for (int e = 0; e < 3; e++)
                ae[i][e] = s_ae[rr][(wid * 5 + i) * 3 + e];
        const float* rm = ds + rr * WW;
        const float* rc = ds + (rr + 1) * WW;
        const float* rp = ds + (rr + 2) * WW;
        #pragma unroll
        for (int j = 0; j < 10; j++) {
            const int x = j * 64 + lane;
            const float px = (float)x;
            const float fl = (x > 0) ? 1.f : 0.f;
            const float fr = (x < WW - 1) ? 1.f : 0.f;
            const int xm = x - (x > 0), xp = x + (x < WW - 1);
            const float a00 = rm[xm] * fl, a01 = rm[x], a02 = rm[xp] * fr;
            const float a10 = rc[xm] * fl,               a12 = rc[xp] * fr;
            const float a20 = rp[xm] * fl, a21 = rp[x], a22 = rp[xp] * fr;
            // XLA conv = cross-correlation, zero pad
            const float gx = (a00 - a02) + 2.f * (a10 - a12) + (a20 - a22);
            const float gy = (a00 + 2.f * a01 + a02) - (a20 + 2.f * a21 + a22);
            const float nx = -gx, ny = -gy;
            const float s2 = nx * nx + ny * ny;
            const bool vm = (vreg[rr][j] != 0);
            #pragma unroll
            for (int i = 0; i < 5; i++) {
                const float d0 = fmaf(-eyr[i][0], px, ae[i][0]);
                const float d1 = fmaf(-eyr[i][1], px, ae[i][1]);
                const float d2 = fmaf(-eyr[i][2], px, ae[i][2]);
                const float dmin = fminf(fminf(d0, d1), d2);
                const float dmax = fmaxf(fmaxf(d0, d1), d2);
                const bool m = ((dmin >= 0.f) | (dmax <= 0.f)) & vm;
                const float mf = m ? 1.f : 0.f;
                acc[i][0] += mf;
                acc[i][1] = fmaf(mf, nx, acc[i][1]);
                acc[i][2] = fmaf(mf, ny, acc[i][2]);
                acc[i][3] = fmaf(mf, s2, acc[i][3]);
            }
        }
    }

    // wave-level reduction; waves own disjoint triangles -> no cross-wave step
    #pragma unroll
    for (int off = 32; off > 0; off >>= 1)
        #pragma unroll
        for (int i = 0; i < 5; i++)
            #pragma unroll
            for (int q = 0; q < 4; q++)
                acc[i][q] += __shfl_down(acc[i][q], off);
    if (lane == 0) {
        // plain stores, zero contention: col = (wid*5+i)*4+q, row = blockIdx.x
        #pragma unroll
        for (int i = 0; i < 5; i++)
            #pragma unroll
            for (int q = 0; q < 4; q++)
                w[((wid * 5 + i) * 4 + q) * NB + blockIdx.x] = acc[i][q];
    }
}

__global__ __launch_bounds__(128) void plane_finalize_kernel(
    const float* __restrict__ line_score, const float* __restrict__ w,
    float* __restrict__ out) {
    __shared__ float s_col[NREF * 4];
    __shared__ int s_cnt[2];
    const int tid = threadIdx.x; // 0..127
    const int lane = tid & 63, wid = tid >> 6;

    // sum partial columns FIRST so the loads issue before the ballot work.
    // (NB contiguous floats each, float4). unroll 15: 15 independent float4
    // loads in flight -> 4 latency round trips. Accumulation order is the
    // same strictly-sequential per-lane order -> bitwise-identical result.
    if (tid < NREF * 4) {
        const float4* col = (const float4*)(w + tid * NB);
        float4 s4 = make_float4(0.f, 0.f, 0.f, 0.f);
        #pragma unroll 15
        for (int p = 0; p < NB / 4; p++) {
            const float4 v = col[p];
            s4.x += v.x; s4.y += v.y; s4.z += v.z; s4.w += v.w;
        }
        s_col[tid] = (s4.x + s4.y) + (s4.z + s4.w);
    }

    // top_num = min(#(softmax prob0 > 0.6), 20); include-flag = (rank < top_num)
    int flag = 0;
    if (tid < NL) {
        const float2 sc = ((const float2*)line_score)[tid];
        const float p0 = 1.0f / (1.0f + expf(sc.y - sc.x));
        flag = (p0 > 0.6f) ? 1 : 0;
    }
    const unsigned long long b = __ballot(flag);
    if (lane == 0) s_cnt[wid] = __popcll(b);
    __syncthreads();

    const int topnum = min(s_cnt[0] + s_cnt[1], NREF);
    float val = 0.f, inc = 0.f;
    if (tid < NREF) {
        const float c  = s_col[tid * 4 + 0];
        const float sx = s_col[tid * 4 + 1];
        const float sy = s_col[tid * 4 + 2];
        const float sq = s_col[tid * 4 + 3];
        const float safe = fmaxf(c, 1.f);
        const float mx = sx / safe, my = sy / safe;
        // (var_x+var_y) expanded; exact 0 when c==0
        const float var = (sq - 2.f * mx * sx - 2.f * my * sy
                           + c * (mx * mx + my * my)) / safe;
        inc = ((c >= 100.f) && (tid < topnum)) ? 1.f : 0.f;
        val = inc * var;
    }
    if (tid < 64) { // lanes 20..63 carry zeros
        #pragma unroll
        for (int off = 32; off > 0; off >>= 1) {
            val += __shfl_down(val, off);
            inc += __shfl_down(inc, off);
        }
        if (tid == 0) out[0] = val / fmaxf(inc, 1.f);
    }
}

extern "C" void kernel_launch(void* const* d_in, const int* in_sizes, int n_in,
                              void* d_out, int out_size, void* d_ws, size_t ws_size,
                              hipStream_t stream) {
    const float* depth_pred = (const float*)d_in[0];
    // d_in[1] = depth_gt (unused by reference)
    const float* line_pred  = (const float*)d_in[2];
    const float* line_score = (const float*)d_in[3];
    const int*   valid_mask = (const int*)d_in[4];
    float* out = (float*)d_out;
    float* w = (float*)d_ws;

    plane_main_kernel<<<NB, 256, 0, stream>>>(depth_pred, valid_mask,
                                              line_pred, line_score, w);
    plane_finalize_kernel<<<1, 128, 0, stream>>>(line_score, w, out);
}